// Round 5
// baseline (145.820 us; speedup 1.0000x reference)
//
#include <hip/hip_runtime.h>

typedef __attribute__((ext_vector_type(8))) short    bf16x8;
typedef __attribute__((ext_vector_type(8))) _Float16 f16x8;
typedef __attribute__((ext_vector_type(4))) float    f32x4;

constexpr int Bsz = 32768;
constexpr int Hn  = 256;
constexpr int In  = 128;
constexpr long long BH = (long long)Bsz * Hn;

// ---------------------------------------------------------------------------
// helpers
// ---------------------------------------------------------------------------
__device__ __forceinline__ unsigned short f2bf(float f) {
    unsigned int u = __float_as_uint(f);
    unsigned int r = (u + 0x7fffu + ((u >> 16) & 1u)) >> 16;   // RNE
    return (unsigned short)r;
}
__device__ __forceinline__ bf16x8 pack8(float4 lo, float4 hi) {
    bf16x8 r;
    r[0] = (short)f2bf(lo.x); r[1] = (short)f2bf(lo.y);
    r[2] = (short)f2bf(lo.z); r[3] = (short)f2bf(lo.w);
    r[4] = (short)f2bf(hi.x); r[5] = (short)f2bf(hi.y);
    r[6] = (short)f2bf(hi.z); r[7] = (short)f2bf(hi.w);
    return r;
}
__device__ __forceinline__ f16x8 packh(float4 lo, float4 hi) {
    f16x8 r;
    r[0] = (_Float16)lo.x; r[1] = (_Float16)lo.y;
    r[2] = (_Float16)lo.z; r[3] = (_Float16)lo.w;
    r[4] = (_Float16)hi.x; r[5] = (_Float16)hi.y;
    r[6] = (_Float16)hi.z; r[7] = (_Float16)hi.w;
    return r;
}
__device__ __forceinline__ f16x8 packh_mid(float4 lo, float4 hi) {
    float f[8] = {lo.x, lo.y, lo.z, lo.w, hi.x, hi.y, hi.z, hi.w};
    f16x8 r;
    #pragma unroll
    for (int k = 0; k < 8; ++k) {
        _Float16 h = (_Float16)f[k];
        r[k] = (_Float16)((f[k] - (float)h) * 4096.0f);   // scaled mid, no subnormals
    }
    return r;
}

// ---------------------------------------------------------------------------
// prep: split/convert weights into workspace (runs once per launch, ~65K thr)
// ws layout (shorts): [0,64K) Gh fp16 | [64K,128K) Gm fp16 (x4096)
//                     [128K,192K) Wr bf16 | [192K,224K) Wi bf16
// ---------------------------------------------------------------------------
__global__ __launch_bounds__(256) void k_prep(
    const float* __restrict__ Wi, const float* __restrict__ Wr,
    const float* __restrict__ Gc, short* __restrict__ ws)
{
    const int idx = blockIdx.x * 256 + threadIdx.x;   // 0..65535
    _Float16* Gh = (_Float16*)ws;
    _Float16* Gm = (_Float16*)(ws + 65536);
    short* Wrb = ws + 131072;
    short* Wib = ws + 196608;
    float g = Gc[idx];
    _Float16 gh = (_Float16)g;
    Gh[idx] = gh;
    Gm[idx] = (_Float16)((g - (float)gh) * 4096.0f);
    Wrb[idx] = (short)f2bf(Wr[idx]);
    if (idx < Hn * In) Wib[idx] = (short)f2bf(Wi[idx]);
}

// ---------------------------------------------------------------------------
// one GEMM phase: acc += conv(A[32 rows x K]) @ Wp[256 x K]^T
// CONV: 0 = bf16 (bf16 MFMA), 1 = fp16 hi, 2 = fp16 mid*4096 (fp16 MFMA)
// Wp is pre-converted 2-byte weights, row-major [256][K].
// LDS: Ab [32][64] 2B swizzled (4 KB) + Wb [256][64] 2B swizzled (32 KB).
// ---------------------------------------------------------------------------
template<int CONV>
__device__ __forceinline__ void gemm_phase(
    const float* __restrict__ A, const short* __restrict__ Wp, int K,
    int rowBase, int tid, char* smem, f32x4 (&acc)[2][4])
{
    short* Ab = (short*)smem;
    short* Wb = (short*)(smem + 4096);
    const int lane = tid & 63;
    const int ln = lane & 15, lg = lane >> 4;
    const int wc = (tid >> 6) * 64;
    const int sar = tid >> 3;          // A-stage row 0..31
    const int sak = (tid & 7) * 8;     // A-stage k offset
    const int wr  = tid >> 3;          // W-stage: chunk-linear, coalesced
    const int wj  = tid & 7;

    #pragma unroll 1
    for (int ks = 0; ks < K; ks += 64) {
        __syncthreads();
        // stage A: 32 rows x 64 k (fp32 -> 2B), coalesced 32B/thread
        {
            const float* src = A + (size_t)(rowBase + sar) * K + ks + sak;
            float4 f0 = *(const float4*)(src);
            float4 f1 = *(const float4*)(src + 4);
            int off = (sar * 128 + sak * 2) ^ ((sar & 7) << 4);
            if constexpr (CONV == 0)
                *(bf16x8*)((char*)Ab + off) = pack8(f0, f1);
            else if constexpr (CONV == 1)
                *(f16x8*)((char*)Ab + off) = packh(f0, f1);
            else
                *(f16x8*)((char*)Ab + off) = packh_mid(f0, f1);
        }
        // stage W: 256 rows x 64 k, pre-converted -> copy 16B chunks, coalesced
        {
            #pragma unroll
            for (int j = 0; j < 8; ++j) {
                const int row = j * 32 + wr;
                bf16x8 w = *(const bf16x8*)(Wp + (size_t)row * K + ks + wj * 8);
                int off = (row * 128 + wj * 16) ^ ((row & 7) << 4);
                *(bf16x8*)((char*)Wb + off) = w;
            }
        }
        __syncthreads();
        // compute: 2 k-steps of 32
        #pragma unroll
        for (int s = 0; s < 2; ++s) {
            const int kb = s * 64 + lg * 16;
            const char* Abc = (const char*)Ab;
            const char* Wbc = (const char*)Wb;
            const int offA0 = ((ln)      * 128 + kb) ^ ((ln & 7) << 4);
            const int offA1 = ((ln + 16) * 128 + kb) ^ ((ln & 7) << 4);
            if constexpr (CONV == 0) {
                bf16x8 a0 = *(const bf16x8*)(Abc + offA0);
                bf16x8 a1 = *(const bf16x8*)(Abc + offA1);
                #pragma unroll
                for (int c = 0; c < 4; ++c) {
                    const int col = wc + c * 16 + ln;
                    bf16x8 b = *(const bf16x8*)(Wbc + ((col * 128 + kb) ^ ((col & 7) << 4)));
                    acc[0][c] = __builtin_amdgcn_mfma_f32_16x16x32_bf16(a0, b, acc[0][c], 0, 0, 0);
                    acc[1][c] = __builtin_amdgcn_mfma_f32_16x16x32_bf16(a1, b, acc[1][c], 0, 0, 0);
                }
            } else {
                f16x8 a0 = *(const f16x8*)(Abc + offA0);
                f16x8 a1 = *(const f16x8*)(Abc + offA1);
                #pragma unroll
                for (int c = 0; c < 4; ++c) {
                    const int col = wc + c * 16 + ln;
                    f16x8 b = *(const f16x8*)(Wbc + ((col * 128 + kb) ^ ((col & 7) << 4)));
                    acc[0][c] = __builtin_amdgcn_mfma_f32_16x16x32_f16(a0, b, acc[0][c], 0, 0, 0);
                    acc[1][c] = __builtin_amdgcn_mfma_f32_16x16x32_f16(a1, b, acc[1][c], 0, 0, 0);
                }
            }
        }
    }
}

// ---------------------------------------------------------------------------
// main: per 32-row stripe, 5 MFMA phases + fused epilogue
//   coupling = v_hi@Gh^T + (v_hi@Gm^T + v_mid@Gh^T)/4096   (fp16 split)
//   acc_i    = x@Wi^T + z@Wr^T                             (bf16)
// ---------------------------------------------------------------------------
__global__ __launch_bounds__(256, 4) void k_main(
    const float* __restrict__ x, const float* __restrict__ z,
    const float* __restrict__ v, const float* __restrict__ cur,
    const float* __restrict__ rho, const short* __restrict__ ws,
    float* __restrict__ out)
{
    __shared__ char smem[36864];
    const int tid = threadIdx.x;
    const int rowBase = blockIdx.x * 32;
    const short* Gh  = ws;
    const short* Gm  = ws + 65536;
    const short* Wrb = ws + 131072;
    const short* Wib = ws + 196608;

    f32x4 acc_c[2][4], acc_cm[2][4];
    #pragma unroll
    for (int m = 0; m < 2; ++m)
        #pragma unroll
        for (int c = 0; c < 4; ++c) {
            acc_c[m][c]  = (f32x4){0.f, 0.f, 0.f, 0.f};
            acc_cm[m][c] = (f32x4){0.f, 0.f, 0.f, 0.f};
        }

    // coupling phases first (then fold, to cap live registers)
    gemm_phase<1>(v, Gh, Hn, rowBase, tid, smem, acc_c);
    gemm_phase<1>(v, Gm, Hn, rowBase, tid, smem, acc_cm);
    gemm_phase<2>(v, Gh, Hn, rowBase, tid, smem, acc_cm);
    #pragma unroll
    for (int m = 0; m < 2; ++m)
        #pragma unroll
        for (int c = 0; c < 4; ++c)
            acc_c[m][c] = acc_c[m][c] + acc_cm[m][c] * 2.44140625e-4f;  // /4096

    f32x4 acc_i[2][4];
    #pragma unroll
    for (int m = 0; m < 2; ++m)
        #pragma unroll
        for (int c = 0; c < 4; ++c) acc_i[m][c] = (f32x4){0.f, 0.f, 0.f, 0.f};
    gemm_phase<0>(x, Wib, In, rowBase, tid, smem, acc_i);
    gemm_phase<0>(z, Wrb, Hn, rowBase, tid, smem, acc_i);

    // epilogue: D map col = lane&15 (+16c+wc), row = rowBase + m*16 + lg*4 + r
    const int lane = tid & 63;
    const int ln = lane & 15, lg = lane >> 4;
    const int wc = (tid >> 6) * 64;
    float* out_z   = out;
    float* out_v   = out + BH;
    float* out_i   = out + 2 * BH;
    float* out_rho = out + 3 * BH;

    #pragma unroll
    for (int m = 0; m < 2; ++m) {
        #pragma unroll
        for (int c = 0; c < 4; ++c) {
            const int col = wc + c * 16 + ln;
            const int rowb = rowBase + m * 16 + lg * 4;
            #pragma unroll
            for (int r = 0; r < 4; ++r) {
                const size_t idx = (size_t)(rowb + r) * Hn + col;
                const float vv = v[idx];
                const float ii = cur[idx];
                const float rh = rho[idx];
                const float coup = acc_c[m][c][r];
                float dv   = 0.1f * ((0.0f - vv) + ii) + coup;
                float vdec = vv + dv;
                float zf   = (vdec - 1.0f) > 0.0f ? 1.0f : 0.0f;
                float vnew = (1.0f - zf) * vdec;              // V_RESET = 0
                float mask = rh > 0.0f ? 1.0f : 0.0f;
                vnew = (1.0f - mask) * vnew + mask * vv;
                zf   = (1.0f - mask) * zf;
                float rhon = (1.0f - zf) * fmaxf(rh - mask, 0.0f) + zf * 5.0f;
                out_z[idx]   = zf;
                out_v[idx]   = vnew;
                out_i[idx]   = 0.8f * ii + acc_i[m][c][r];
                out_rho[idx] = rhon;
            }
        }
    }
}

extern "C" void kernel_launch(void* const* d_in, const int* in_sizes, int n_in,
                              void* d_out, int out_size, void* d_ws, size_t ws_size,
                              hipStream_t stream) {
    const float* x   = (const float*)d_in[0];
    const float* z   = (const float*)d_in[1];
    const float* v   = (const float*)d_in[2];
    const float* cur = (const float*)d_in[3];
    const float* rho = (const float*)d_in[4];
    const float* Wi  = (const float*)d_in[5];
    const float* Wr  = (const float*)d_in[6];
    const float* Gc  = (const float*)d_in[7];
    float* out = (float*)d_out;
    short* ws  = (short*)d_ws;   // needs 458752 B

    hipLaunchKernelGGL(k_prep, dim3(256), dim3(256), 0, stream, Wi, Wr, Gc, ws);
    hipLaunchKernelGGL(k_main, dim3(Bsz / 32), dim3(256), 0, stream,
                       x, z, v, cur, rho, ws, out);
}